// Round 1
// baseline (796.655 us; speedup 1.0000x reference)
//
#include <hip/hip_runtime.h>
#include <math.h>

#define NEG_SLOPE 0.2f
#define SM_EPS 1e-16f

// ---------------- helpers ----------------

__device__ inline void atomicMaxFloat(float* addr, float val) {
    int iv = __float_as_int(val);
    if (iv == (int)0x80000000) iv = 0;  // canonicalize -0.0 -> +0.0
    if (iv >= 0) atomicMax((int*)addr, iv);
    else atomicMin((unsigned int*)addr, (unsigned int)iv);
}

__device__ inline void get_edge(const int* __restrict__ srcA, const int* __restrict__ dstA,
                                int e, int E, int& s, int& d) {
    if (e < E) { s = srcA[e]; d = dstA[e]; }
    else { s = e - E; d = e - E; }   // self-loops appended after real edges
}

// ---------------- init ----------------

__global__ __launch_bounds__(256) void k_init(float* m1, float* d1, float* m2, float* d2,
                                              int* deg, int N) {
    int i = blockIdx.x * 256 + threadIdx.x;
    if (i < N * 8) { m1[i] = -INFINITY; d1[i] = 0.f; }
    if (i < N)     { m2[i] = -INFINITY; d2[i] = 0.f; deg[i] = 0; }
}

// ---------------- CSR build ----------------

__global__ __launch_bounds__(256) void k_deg(const int* __restrict__ dstA, int E, int Ep,
                                             int* __restrict__ deg) {
    int e = blockIdx.x * 256 + threadIdx.x;
    if (e >= Ep) return;
    int d = (e < E) ? dstA[e] : (e - E);
    atomicAdd(&deg[d], 1);
}

__global__ __launch_bounds__(256) void k_scan1(const int* __restrict__ deg, int* __restrict__ incl,
                                               int* __restrict__ part, int N) {
    __shared__ int sm[256];
    int t = threadIdx.x;
    int i = blockIdx.x * 256 + t;
    int v = (i < N) ? deg[i] : 0;
    sm[t] = v; __syncthreads();
    for (int o = 1; o < 256; o <<= 1) {
        int x = (t >= o) ? sm[t - o] : 0;
        __syncthreads();
        sm[t] += x;
        __syncthreads();
    }
    if (i < N) incl[i] = sm[t];
    if (t == 255) part[blockIdx.x] = sm[255];
}

__global__ __launch_bounds__(256) void k_scan2(int* __restrict__ part, int nb) {
    __shared__ int sm[256];
    int t = threadIdx.x;
    int v = (t < nb) ? part[t] : 0;
    sm[t] = v; __syncthreads();
    for (int o = 1; o < 256; o <<= 1) {
        int x = (t >= o) ? sm[t - o] : 0;
        __syncthreads();
        sm[t] += x;
        __syncthreads();
    }
    if (t < nb) part[t] = sm[t] - v;   // exclusive
}

__global__ __launch_bounds__(256) void k_scan3(const int* __restrict__ incl, const int* __restrict__ part,
                                               const int* __restrict__ deg, int* __restrict__ off,
                                               int* __restrict__ cursor, int N) {
    int i = blockIdx.x * 256 + threadIdx.x;
    if (i >= N) return;
    int v = incl[i] + part[blockIdx.x];   // inclusive scan value
    off[i + 1] = v;
    cursor[i] = v - deg[i];
    if (i == 0) off[0] = 0;
}

__global__ __launch_bounds__(256) void k_scatter(const int* __restrict__ srcA, const int* __restrict__ dstA,
                                                 int E, int Ep, int* __restrict__ cursor,
                                                 int* __restrict__ eid_s, int* __restrict__ src_s) {
    int e = blockIdx.x * 256 + threadIdx.x;
    if (e >= Ep) return;
    int s, d; get_edge(srcA, dstA, e, E, s, d);
    int p = atomicAdd(&cursor[d], 1);
    eid_s[p] = e;
    src_s[p] = s;
}

// ---------------- GEMM1: xw1 = x @ W1  (Mx512 @ 512x512) ----------------

__global__ __launch_bounds__(256) void k_gemm1(const float* __restrict__ A, const float* __restrict__ B,
                                               float* __restrict__ C, int M) {
    const int K = 512, Nc = 512;
    __shared__ float As[16][68];
    __shared__ float Bs[16][68];
    int tid = threadIdx.x;
    int row0 = blockIdx.x * 64, col0 = blockIdx.y * 64;
    int tx = tid % 16, ty = tid / 16;
    int la_row = tid / 4, la_k4 = (tid % 4) * 4;
    int lb_k = tid / 16, lb_c4 = (tid % 16) * 4;
    float acc[4][4] = {};
    for (int k0 = 0; k0 < K; k0 += 16) {
        float4 av = make_float4(0.f, 0.f, 0.f, 0.f);
        int ar = row0 + la_row;
        if (ar < M) av = *(const float4*)(A + (size_t)ar * K + k0 + la_k4);
        As[la_k4 + 0][la_row] = av.x;
        As[la_k4 + 1][la_row] = av.y;
        As[la_k4 + 2][la_row] = av.z;
        As[la_k4 + 3][la_row] = av.w;
        float4 bv = *(const float4*)(B + (size_t)(k0 + lb_k) * Nc + col0 + lb_c4);
        *(float4*)&Bs[lb_k][lb_c4] = bv;
        __syncthreads();
        #pragma unroll
        for (int k = 0; k < 16; ++k) {
            float a[4], b[4];
            #pragma unroll
            for (int i = 0; i < 4; ++i) a[i] = As[k][ty * 4 + i];
            #pragma unroll
            for (int j = 0; j < 4; ++j) b[j] = Bs[k][tx * 4 + j];
            #pragma unroll
            for (int i = 0; i < 4; ++i)
                #pragma unroll
                for (int j = 0; j < 4; ++j)
                    acc[i][j] = fmaf(a[i], b[j], acc[i][j]);
        }
        __syncthreads();
    }
    #pragma unroll
    for (int i = 0; i < 4; ++i) {
        int r = row0 + ty * 4 + i;
        if (r < M) {
            float4 v = make_float4(acc[i][0], acc[i][1], acc[i][2], acc[i][3]);
            *(float4*)(C + (size_t)r * Nc + col0 + tx * 4) = v;
        }
    }
}

// ---------------- attention dots ----------------

// layer 1: one 64-lane wave per (n,h); H=8, C=64
__global__ __launch_bounds__(256) void k_attn1(const float* __restrict__ xw, const float* __restrict__ att_s,
                                               const float* __restrict__ att_d, float* __restrict__ a_s,
                                               float* __restrict__ a_d, int N) {
    int wid = (blockIdx.x * 256 + threadIdx.x) >> 6;
    int lane = threadIdx.x & 63;
    int n = wid >> 3, h = wid & 7;
    if (n >= N) return;
    float v = xw[(size_t)n * 512 + h * 64 + lane];
    float ps = v * att_s[h * 64 + lane];
    float pd = v * att_d[h * 64 + lane];
    #pragma unroll
    for (int m = 32; m >= 1; m >>= 1) {
        ps += __shfl_xor(ps, m);
        pd += __shfl_xor(pd, m);
    }
    if (lane == 0) { a_s[n * 8 + h] = ps; a_d[n * 8 + h] = pd; }
}

// layer 2: 32 lanes per node; H=1, C=32
__global__ __launch_bounds__(256) void k_attn2(const float* __restrict__ hw2, const float* __restrict__ att_s,
                                               const float* __restrict__ att_d, float* __restrict__ a_s,
                                               float* __restrict__ a_d, int N) {
    int idx = blockIdx.x * 256 + threadIdx.x;
    int n = idx >> 5, lane = idx & 31;
    if (n >= N) return;
    float v = hw2[(size_t)n * 32 + lane];
    float ps = v * att_s[lane];
    float pd = v * att_d[lane];
    #pragma unroll
    for (int m = 16; m >= 1; m >>= 1) {
        ps += __shfl_xor(ps, m, 32);
        pd += __shfl_xor(pd, m, 32);
    }
    if (lane == 0) { a_s[n] = ps; a_d[n] = pd; }
}

// ---------------- edge softmax ----------------

template <int H>
__global__ __launch_bounds__(256) void k_edge_max(const int* __restrict__ srcA, const int* __restrict__ dstA,
                                                  int E, int Ep, const float* __restrict__ a_s,
                                                  const float* __restrict__ a_d, float* __restrict__ mbuf) {
    int e = blockIdx.x * 256 + threadIdx.x;
    if (e >= Ep) return;
    int s, d; get_edge(srcA, dstA, e, E, s, d);
    #pragma unroll
    for (int h = 0; h < H; ++h) {
        float v = a_s[s * H + h] + a_d[d * H + h];
        v = v > 0.f ? v : NEG_SLOPE * v;
        atomicMaxFloat(&mbuf[d * H + h], v);
    }
}

template <int H>
__global__ __launch_bounds__(256) void k_edge_expsum(const int* __restrict__ srcA, const int* __restrict__ dstA,
                                                     int E, int Ep, const float* __restrict__ a_s,
                                                     const float* __restrict__ a_d, const float* __restrict__ mbuf,
                                                     float* __restrict__ wbuf, float* __restrict__ denom) {
    int e = blockIdx.x * 256 + threadIdx.x;
    if (e >= Ep) return;
    int s, d; get_edge(srcA, dstA, e, E, s, d);
    #pragma unroll
    for (int h = 0; h < H; ++h) {
        float v = a_s[s * H + h] + a_d[d * H + h];
        v = v > 0.f ? v : NEG_SLOPE * v;
        float wv = expf(v - mbuf[d * H + h]);
        wbuf[(size_t)e * H + h] = wv;
        atomicAdd(&denom[d * H + h], wv);
    }
}

// ---------------- aggregation ----------------

// layer 1: one block per node; thread t covers channels t and t+256 of the 512
__global__ __launch_bounds__(256) void k_agg1(const float* __restrict__ xw, const float* __restrict__ wbuf,
                                              const float* __restrict__ denom, const int* __restrict__ off,
                                              const int* __restrict__ eid_s, const int* __restrict__ src_s,
                                              const float* __restrict__ bias, float* __restrict__ hout, int N) {
    int n = blockIdx.x;
    int t = threadIdx.x;
    int h0 = t >> 6;       // 0..3
    int h1 = h0 + 4;       // 4..7
    float inv0 = 1.f / (denom[n * 8 + h0] + SM_EPS);
    float inv1 = 1.f / (denom[n * 8 + h1] + SM_EPS);
    float acc0 = 0.f, acc1 = 0.f;
    int p0 = off[n], p1 = off[n + 1];
    for (int p = p0; p < p1; ++p) {
        int s = src_s[p];
        int eid = eid_s[p];
        float w0 = wbuf[(size_t)eid * 8 + h0];
        float w1 = wbuf[(size_t)eid * 8 + h1];
        const float* xr = xw + (size_t)s * 512;
        acc0 = fmaf(w0, xr[t], acc0);
        acc1 = fmaf(w1, xr[t + 256], acc1);
    }
    acc0 = acc0 * inv0 + bias[t];
    acc1 = acc1 * inv1 + bias[t + 256];
    hout[(size_t)n * 512 + t]       = acc0 > 0.f ? acc0 : expm1f(acc0);
    hout[(size_t)n * 512 + t + 256] = acc1 > 0.f ? acc1 : expm1f(acc1);
}

// ---------------- GEMM2: hw2 = h @ W2  (Mx512 @ 512x32) ----------------

__global__ __launch_bounds__(256) void k_gemm2(const float* __restrict__ Hm, const float* __restrict__ W2,
                                               float* __restrict__ O, int M) {
    __shared__ float hs[8][512];
    int tid = threadIdx.x;
    int n0 = blockIdx.x * 8;
    for (int i = tid; i < 8 * 512; i += 256) {
        int r = i >> 9, c = i & 511;
        int gr = n0 + r;
        hs[r][c] = (gr < M) ? Hm[(size_t)gr * 512 + c] : 0.f;
    }
    __syncthreads();
    int r = tid >> 5, c = tid & 31;
    float acc = 0.f;
    #pragma unroll 8
    for (int k = 0; k < 512; ++k)
        acc = fmaf(hs[r][k], W2[k * 32 + c], acc);
    int gr = n0 + r;
    if (gr < M) O[(size_t)gr * 32 + c] = acc;
}

// layer 2 aggregation + bias + log_softmax -> d_out. 32 lanes per node, 8 nodes/block.
__global__ __launch_bounds__(256) void k_agg2(const float* __restrict__ hw2, const float* __restrict__ wbuf,
                                              const float* __restrict__ denom, const int* __restrict__ off,
                                              const int* __restrict__ eid_s, const int* __restrict__ src_s,
                                              const float* __restrict__ bias, float* __restrict__ outp, int N) {
    int sub = threadIdx.x >> 5;
    int lane = threadIdx.x & 31;
    int n = blockIdx.x * 8 + sub;
    if (n >= N) return;
    float inv = 1.f / (denom[n] + SM_EPS);
    float acc = 0.f;
    int p0 = off[n], p1 = off[n + 1];
    for (int p = p0; p < p1; ++p) {
        int s = src_s[p];
        int eid = eid_s[p];
        acc = fmaf(wbuf[eid], hw2[(size_t)s * 32 + lane], acc);
    }
    acc = acc * inv + bias[lane];
    float mx = acc;
    #pragma unroll
    for (int m = 16; m >= 1; m >>= 1) mx = fmaxf(mx, __shfl_xor(mx, m, 32));
    float ex = expf(acc - mx);
    float sum = ex;
    #pragma unroll
    for (int m = 16; m >= 1; m >>= 1) sum += __shfl_xor(sum, m, 32);
    outp[(size_t)n * 32 + lane] = (acc - mx) - logf(sum);
}

// ---------------- launch ----------------

extern "C" void kernel_launch(void* const* d_in, const int* in_sizes, int n_in,
                              void* d_out, int out_size, void* d_ws, size_t ws_size,
                              hipStream_t stream) {
    const float* x   = (const float*)d_in[0];
    const int*   ei  = (const int*)d_in[1];
    const float* W1  = (const float*)d_in[2];
    const float* as1 = (const float*)d_in[3];
    const float* ad1 = (const float*)d_in[4];
    const float* b1  = (const float*)d_in[5];
    const float* W2  = (const float*)d_in[6];
    const float* as2 = (const float*)d_in[7];
    const float* ad2 = (const float*)d_in[8];
    const float* b2  = (const float*)d_in[9];
    float* out = (float*)d_out;

    const int F = 512;
    const int N = in_sizes[0] / F;     // 20000
    const int E = in_sizes[1] / 2;     // 320000
    const int Ep = E + N;              // with self-loops
    const int* srcA = ei;
    const int* dstA = ei + E;

    char* w = (char*)d_ws;
    auto alloc = [&](size_t b) -> void* {
        void* p = (void*)w;
        w += (b + 255) & ~(size_t)255;
        return p;
    };
    float* xw1  = (float*)alloc((size_t)N * 512 * 4);
    float* hbuf = (float*)alloc((size_t)N * 512 * 4);
    float* a_s1 = (float*)alloc((size_t)N * 8 * 4);
    float* a_d1 = (float*)alloc((size_t)N * 8 * 4);
    float* m1   = (float*)alloc((size_t)N * 8 * 4);
    float* d1   = (float*)alloc((size_t)N * 8 * 4);
    float* wb1  = (float*)alloc((size_t)Ep * 8 * 4);
    float* hw2  = (float*)alloc((size_t)N * 32 * 4);
    float* a_s2 = (float*)alloc((size_t)N * 4);
    float* a_d2 = (float*)alloc((size_t)N * 4);
    float* m2   = (float*)alloc((size_t)N * 4);
    float* d2   = (float*)alloc((size_t)N * 4);
    float* wb2  = (float*)alloc((size_t)Ep * 4);
    int* deg    = (int*)alloc((size_t)N * 4);
    int* incl   = (int*)alloc((size_t)N * 4);
    int* part   = (int*)alloc(256 * 4);
    int* off    = (int*)alloc((size_t)(N + 1) * 4);
    int* cursor = (int*)alloc((size_t)N * 4);
    int* eid_s  = (int*)alloc((size_t)Ep * 4);
    int* src_s  = (int*)alloc((size_t)Ep * 4);

    int egrid = (Ep + 255) / 256;
    int sgrid = (N + 255) / 256;

    k_init<<<(N * 8 + 255) / 256, 256, 0, stream>>>(m1, d1, m2, d2, deg, N);

    // CSR (shared by both layers)
    k_deg<<<egrid, 256, 0, stream>>>(dstA, E, Ep, deg);
    k_scan1<<<sgrid, 256, 0, stream>>>(deg, incl, part, N);
    k_scan2<<<1, 256, 0, stream>>>(part, sgrid);
    k_scan3<<<sgrid, 256, 0, stream>>>(incl, part, deg, off, cursor, N);
    k_scatter<<<egrid, 256, 0, stream>>>(srcA, dstA, E, Ep, cursor, eid_s, src_s);

    // layer 1
    dim3 g1((N + 63) / 64, 512 / 64);
    k_gemm1<<<g1, 256, 0, stream>>>(x, W1, xw1, N);
    k_attn1<<<(N * 8 + 3) / 4, 256, 0, stream>>>(xw1, as1, ad1, a_s1, a_d1, N);
    k_edge_max<8><<<egrid, 256, 0, stream>>>(srcA, dstA, E, Ep, a_s1, a_d1, m1);
    k_edge_expsum<8><<<egrid, 256, 0, stream>>>(srcA, dstA, E, Ep, a_s1, a_d1, m1, wb1, d1);
    k_agg1<<<N, 256, 0, stream>>>(xw1, wb1, d1, off, eid_s, src_s, b1, hbuf, N);

    // layer 2
    k_gemm2<<<(N + 7) / 8, 256, 0, stream>>>(hbuf, W2, hw2, N);
    k_attn2<<<(N * 32 + 255) / 256, 256, 0, stream>>>(hw2, as2, ad2, a_s2, a_d2, N);
    k_edge_max<1><<<egrid, 256, 0, stream>>>(srcA, dstA, E, Ep, a_s2, a_d2, m2);
    k_edge_expsum<1><<<egrid, 256, 0, stream>>>(srcA, dstA, E, Ep, a_s2, a_d2, m2, wb2, d2);
    k_agg2<<<(N + 7) / 8, 256, 0, stream>>>(hw2, wb2, d2, off, eid_s, src_s, b2, out, N);
}

// Round 2
// 659.269 us; speedup vs baseline: 1.2084x; 1.2084x over previous
//
#include <hip/hip_runtime.h>
#include <math.h>

#define NEG_SLOPE 0.2f
#define SM_EPS 1e-16f

typedef short short8 __attribute__((ext_vector_type(8)));
typedef float floatx4 __attribute__((ext_vector_type(4)));

// ---------------- helpers ----------------

__device__ inline unsigned short f2bf(float x) {
    unsigned int u = __float_as_uint(x);
    unsigned int r = (u + 0x7FFFu + ((u >> 16) & 1u)) >> 16;
    return (unsigned short)r;
}

__device__ inline float bf2f(unsigned short h) {
    return __uint_as_float(((unsigned int)h) << 16);
}

__device__ inline void atomicMaxFloat(float* addr, float val) {
    int iv = __float_as_int(val);
    if (iv == (int)0x80000000) iv = 0;  // canonicalize -0.0 -> +0.0
    if (iv >= 0) atomicMax((int*)addr, iv);
    else atomicMin((unsigned int*)addr, (unsigned int)iv);
}

__device__ inline void get_edge(const int* __restrict__ srcA, const int* __restrict__ dstA,
                                int e, int E, int& s, int& d) {
    if (e < E) { s = srcA[e]; d = dstA[e]; }
    else { s = e - E; d = e - E; }   // self-loops appended after real edges
}

// ---------------- init ----------------

__global__ __launch_bounds__(256) void k_init(float* m1, float* d1, float* m2, float* d2,
                                              int* deg, int N) {
    int i = blockIdx.x * 256 + threadIdx.x;
    if (i < N * 8) { m1[i] = -INFINITY; d1[i] = 0.f; }
    if (i < N)     { m2[i] = -INFINITY; d2[i] = 0.f; deg[i] = 0; }
}

// ---------------- casts ----------------

__global__ __launch_bounds__(256) void k_cast_x(const float* __restrict__ x,
                                                unsigned short* __restrict__ xb, int total4) {
    int i = (blockIdx.x * 256 + threadIdx.x) * 4;
    if (i >= total4 * 4) return;
    float4 v = *(const float4*)(x + i);
    ushort4 o;
    o.x = f2bf(v.x); o.y = f2bf(v.y); o.z = f2bf(v.z); o.w = f2bf(v.w);
    *(ushort4*)(xb + i) = o;
}

// W1 is [K=512][N=512]; produce W1t bf16 [n][k]
__global__ __launch_bounds__(256) void k_cast_w1t(const float* __restrict__ W,
                                                  unsigned short* __restrict__ Wt) {
    __shared__ float tile[32][33];
    int bx = blockIdx.x * 32;   // k base
    int by = blockIdx.y * 32;   // n base
    int tx = threadIdx.x & 31, ty = threadIdx.x >> 5;  // 32x8
    #pragma unroll
    for (int i = 0; i < 32; i += 8)
        tile[ty + i][tx] = W[(size_t)(bx + ty + i) * 512 + by + tx];
    __syncthreads();
    #pragma unroll
    for (int i = 0; i < 32; i += 8)
        Wt[(size_t)(by + ty + i) * 512 + bx + tx] = f2bf(tile[tx][ty + i]);
}

// ---------------- CSR build ----------------

__global__ __launch_bounds__(256) void k_deg(const int* __restrict__ dstA, int E, int Ep,
                                             int* __restrict__ deg) {
    int e = blockIdx.x * 256 + threadIdx.x;
    if (e >= Ep) return;
    int d = (e < E) ? dstA[e] : (e - E);
    atomicAdd(&deg[d], 1);
}

__global__ __launch_bounds__(256) void k_scan1(const int* __restrict__ deg, int* __restrict__ incl,
                                               int* __restrict__ part, int N) {
    __shared__ int sm[256];
    int t = threadIdx.x;
    int i = blockIdx.x * 256 + t;
    int v = (i < N) ? deg[i] : 0;
    sm[t] = v; __syncthreads();
    for (int o = 1; o < 256; o <<= 1) {
        int x = (t >= o) ? sm[t - o] : 0;
        __syncthreads();
        sm[t] += x;
        __syncthreads();
    }
    if (i < N) incl[i] = sm[t];
    if (t == 255) part[blockIdx.x] = sm[255];
}

__global__ __launch_bounds__(256) void k_scan2(int* __restrict__ part, int nb) {
    __shared__ int sm[256];
    int t = threadIdx.x;
    int v = (t < nb) ? part[t] : 0;
    sm[t] = v; __syncthreads();
    for (int o = 1; o < 256; o <<= 1) {
        int x = (t >= o) ? sm[t - o] : 0;
        __syncthreads();
        sm[t] += x;
        __syncthreads();
    }
    if (t < nb) part[t] = sm[t] - v;   // exclusive
}

__global__ __launch_bounds__(256) void k_scan3(const int* __restrict__ incl, const int* __restrict__ part,
                                               const int* __restrict__ deg, int* __restrict__ off,
                                               int* __restrict__ cursor, int N) {
    int i = blockIdx.x * 256 + threadIdx.x;
    if (i >= N) return;
    int v = incl[i] + part[blockIdx.x];   // inclusive scan value
    off[i + 1] = v;
    cursor[i] = v - deg[i];
    if (i == 0) off[0] = 0;
}

__global__ __launch_bounds__(256) void k_scatter(const int* __restrict__ srcA, const int* __restrict__ dstA,
                                                 int E, int Ep, int* __restrict__ cursor,
                                                 int* __restrict__ eid_s, int* __restrict__ src_s) {
    int e = blockIdx.x * 256 + threadIdx.x;
    if (e >= Ep) return;
    int s, d; get_edge(srcA, dstA, e, E, s, d);
    int p = atomicAdd(&cursor[d], 1);
    eid_s[p] = e;
    src_s[p] = s;
}

// ---------------- GEMM1 (bf16 MFMA): xw1 = x @ W1, output bf16 ----------------
// A: M x 512 bf16 row-major. Bt: 512 x 512 bf16, n-major (Bt[n][k] = W1[k][n]).
// C: M x 512 bf16. 128x128 tile per block, 4 waves in 2x2, each wave 64x64 via
// 4x4 grid of 16x16x32 MFMAs.

__global__ __launch_bounds__(256) void k_gemm1_mfma(const unsigned short* __restrict__ A,
                                                    const unsigned short* __restrict__ Bt,
                                                    unsigned short* __restrict__ C, int M) {
    const int K = 512;
    // +8 bf16 padding on the 32-wide k dim -> stride 40 (80 B) kills b128 conflicts
    __shared__ unsigned short As[128 * 40];
    __shared__ unsigned short Bs[128 * 40];
    int t = threadIdx.x;
    int lane = t & 63;
    int w = t >> 6;
    int row0 = blockIdx.x * 128;
    int col0 = blockIdx.y * 128;
    int wm = (w >> 1) * 64, wn = (w & 1) * 64;
    int l15 = lane & 15, q = lane >> 4;

    floatx4 acc[4][4] = {};

    for (int k0 = 0; k0 < K; k0 += 32) {
        #pragma unroll
        for (int r = 0; r < 2; ++r) {
            int flat = r * 2048 + t * 8;
            int m = flat >> 5, kk = flat & 31;
            uint4 va = make_uint4(0u, 0u, 0u, 0u);
            int gr = row0 + m;
            if (gr < M) va = *(const uint4*)(A + (size_t)gr * K + k0 + kk);
            *(uint4*)(&As[m * 40 + kk]) = va;
            uint4 vb = *(const uint4*)(Bt + (size_t)(col0 + m) * K + k0 + kk);
            *(uint4*)(&Bs[m * 40 + kk]) = vb;
        }
        __syncthreads();
        short8 af[4], bfr[4];
        #pragma unroll
        for (int i = 0; i < 4; ++i)
            af[i] = *(const short8*)(&As[(wm + i * 16 + l15) * 40 + q * 8]);
        #pragma unroll
        for (int j = 0; j < 4; ++j)
            bfr[j] = *(const short8*)(&Bs[(wn + j * 16 + l15) * 40 + q * 8]);
        #pragma unroll
        for (int i = 0; i < 4; ++i)
            #pragma unroll
            for (int j = 0; j < 4; ++j)
                acc[i][j] = __builtin_amdgcn_mfma_f32_16x16x32_bf16(af[i], bfr[j], acc[i][j], 0, 0, 0);
        __syncthreads();
    }
    // C/D layout: col = lane&15, row = (lane>>4)*4 + reg
    #pragma unroll
    for (int i = 0; i < 4; ++i) {
        #pragma unroll
        for (int p = 0; p < 4; ++p) {
            int r = row0 + wm + i * 16 + q * 4 + p;
            if (r < M) {
                #pragma unroll
                for (int j = 0; j < 4; ++j) {
                    int c = col0 + wn + j * 16 + l15;
                    C[(size_t)r * 512 + c] = f2bf(acc[i][j][p]);
                }
            }
        }
    }
}

// ---------------- attention dots ----------------

// layer 1: one 64-lane wave per (n,h); H=8, C=64; xw is bf16
__global__ __launch_bounds__(256) void k_attn1(const unsigned short* __restrict__ xw,
                                               const float* __restrict__ att_s,
                                               const float* __restrict__ att_d, float* __restrict__ a_s,
                                               float* __restrict__ a_d, int N) {
    int wid = (blockIdx.x * 256 + threadIdx.x) >> 6;
    int lane = threadIdx.x & 63;
    int n = wid >> 3, h = wid & 7;
    if (n >= N) return;
    float v = bf2f(xw[(size_t)n * 512 + h * 64 + lane]);
    float ps = v * att_s[h * 64 + lane];
    float pd = v * att_d[h * 64 + lane];
    #pragma unroll
    for (int m = 32; m >= 1; m >>= 1) {
        ps += __shfl_xor(ps, m);
        pd += __shfl_xor(pd, m);
    }
    if (lane == 0) { a_s[n * 8 + h] = ps; a_d[n * 8 + h] = pd; }
}

// layer 2: 32 lanes per node; H=1, C=32
__global__ __launch_bounds__(256) void k_attn2(const float* __restrict__ hw2, const float* __restrict__ att_s,
                                               const float* __restrict__ att_d, float* __restrict__ a_s,
                                               float* __restrict__ a_d, int N) {
    int idx = blockIdx.x * 256 + threadIdx.x;
    int n = idx >> 5, lane = idx & 31;
    if (n >= N) return;
    float v = hw2[(size_t)n * 32 + lane];
    float ps = v * att_s[lane];
    float pd = v * att_d[lane];
    #pragma unroll
    for (int m = 16; m >= 1; m >>= 1) {
        ps += __shfl_xor(ps, m, 32);
        pd += __shfl_xor(pd, m, 32);
    }
    if (lane == 0) { a_s[n] = ps; a_d[n] = pd; }
}

// ---------------- edge softmax ----------------

template <int H>
__global__ __launch_bounds__(256) void k_edge_max(const int* __restrict__ srcA, const int* __restrict__ dstA,
                                                  int E, int Ep, const float* __restrict__ a_s,
                                                  const float* __restrict__ a_d, float* __restrict__ mbuf) {
    int e = blockIdx.x * 256 + threadIdx.x;
    if (e >= Ep) return;
    int s, d; get_edge(srcA, dstA, e, E, s, d);
    #pragma unroll
    for (int h = 0; h < H; ++h) {
        float v = a_s[s * H + h] + a_d[d * H + h];
        v = v > 0.f ? v : NEG_SLOPE * v;
        atomicMaxFloat(&mbuf[d * H + h], v);
    }
}

template <int H>
__global__ __launch_bounds__(256) void k_edge_expsum(const int* __restrict__ srcA, const int* __restrict__ dstA,
                                                     int E, int Ep, const float* __restrict__ a_s,
                                                     const float* __restrict__ a_d, const float* __restrict__ mbuf,
                                                     float* __restrict__ wbuf, float* __restrict__ denom) {
    int e = blockIdx.x * 256 + threadIdx.x;
    if (e >= Ep) return;
    int s, d; get_edge(srcA, dstA, e, E, s, d);
    #pragma unroll
    for (int h = 0; h < H; ++h) {
        float v = a_s[s * H + h] + a_d[d * H + h];
        v = v > 0.f ? v : NEG_SLOPE * v;
        float wv = expf(v - mbuf[d * H + h]);
        wbuf[(size_t)e * H + h] = wv;
        atomicAdd(&denom[d * H + h], wv);
    }
}

// ---------------- aggregation ----------------

// layer 1: one block per node; thread t covers channels t and t+256; xw is bf16
__global__ __launch_bounds__(256) void k_agg1(const unsigned short* __restrict__ xw,
                                              const float* __restrict__ wbuf,
                                              const float* __restrict__ denom, const int* __restrict__ off,
                                              const int* __restrict__ eid_s, const int* __restrict__ src_s,
                                              const float* __restrict__ bias, float* __restrict__ hout, int N) {
    int n = blockIdx.x;
    int t = threadIdx.x;
    int h0 = t >> 6;       // 0..3
    int h1 = h0 + 4;       // 4..7
    float inv0 = 1.f / (denom[n * 8 + h0] + SM_EPS);
    float inv1 = 1.f / (denom[n * 8 + h1] + SM_EPS);
    float acc0 = 0.f, acc1 = 0.f;
    int p0 = off[n], p1 = off[n + 1];
    for (int p = p0; p < p1; ++p) {
        int s = src_s[p];
        int eid = eid_s[p];
        float w0 = wbuf[(size_t)eid * 8 + h0];
        float w1 = wbuf[(size_t)eid * 8 + h1];
        const unsigned short* xr = xw + (size_t)s * 512;
        acc0 = fmaf(w0, bf2f(xr[t]), acc0);
        acc1 = fmaf(w1, bf2f(xr[t + 256]), acc1);
    }
    acc0 = acc0 * inv0 + bias[t];
    acc1 = acc1 * inv1 + bias[t + 256];
    hout[(size_t)n * 512 + t]       = acc0 > 0.f ? acc0 : expm1f(acc0);
    hout[(size_t)n * 512 + t + 256] = acc1 > 0.f ? acc1 : expm1f(acc1);
}

// ---------------- GEMM2: hw2 = h @ W2  (Mx512 @ 512x32) ----------------

__global__ __launch_bounds__(256) void k_gemm2(const float* __restrict__ Hm, const float* __restrict__ W2,
                                               float* __restrict__ O, int M) {
    __shared__ float hs[8][512];
    int tid = threadIdx.x;
    int n0 = blockIdx.x * 8;
    for (int i = tid; i < 8 * 512; i += 256) {
        int r = i >> 9, c = i & 511;
        int gr = n0 + r;
        hs[r][c] = (gr < M) ? Hm[(size_t)gr * 512 + c] : 0.f;
    }
    __syncthreads();
    int r = tid >> 5, c = tid & 31;
    float acc = 0.f;
    #pragma unroll 8
    for (int k = 0; k < 512; ++k)
        acc = fmaf(hs[r][k], W2[k * 32 + c], acc);
    int gr = n0 + r;
    if (gr < M) O[(size_t)gr * 32 + c] = acc;
}

// layer 2 aggregation + bias + log_softmax -> d_out. 32 lanes per node, 8 nodes/block.
__global__ __launch_bounds__(256) void k_agg2(const float* __restrict__ hw2, const float* __restrict__ wbuf,
                                              const float* __restrict__ denom, const int* __restrict__ off,
                                              const int* __restrict__ eid_s, const int* __restrict__ src_s,
                                              const float* __restrict__ bias, float* __restrict__ outp, int N) {
    int sub = threadIdx.x >> 5;
    int lane = threadIdx.x & 31;
    int n = blockIdx.x * 8 + sub;
    if (n >= N) return;
    float inv = 1.f / (denom[n] + SM_EPS);
    float acc = 0.f;
    int p0 = off[n], p1 = off[n + 1];
    for (int p = p0; p < p1; ++p) {
        int s = src_s[p];
        int eid = eid_s[p];
        acc = fmaf(wbuf[eid], hw2[(size_t)s * 32 + lane], acc);
    }
    acc = acc * inv + bias[lane];
    float mx = acc;
    #pragma unroll
    for (int m = 16; m >= 1; m >>= 1) mx = fmaxf(mx, __shfl_xor(mx, m, 32));
    float ex = expf(acc - mx);
    float sum = ex;
    #pragma unroll
    for (int m = 16; m >= 1; m >>= 1) sum += __shfl_xor(sum, m, 32);
    outp[(size_t)n * 32 + lane] = (acc - mx) - logf(sum);
}

// ---------------- launch ----------------

extern "C" void kernel_launch(void* const* d_in, const int* in_sizes, int n_in,
                              void* d_out, int out_size, void* d_ws, size_t ws_size,
                              hipStream_t stream) {
    const float* x   = (const float*)d_in[0];
    const int*   ei  = (const int*)d_in[1];
    const float* W1  = (const float*)d_in[2];
    const float* as1 = (const float*)d_in[3];
    const float* ad1 = (const float*)d_in[4];
    const float* b1  = (const float*)d_in[5];
    const float* W2  = (const float*)d_in[6];
    const float* as2 = (const float*)d_in[7];
    const float* ad2 = (const float*)d_in[8];
    const float* b2  = (const float*)d_in[9];
    float* out = (float*)d_out;

    const int F = 512;
    const int N = in_sizes[0] / F;     // 20000
    const int E = in_sizes[1] / 2;     // 320000
    const int Ep = E + N;              // with self-loops
    const int* srcA = ei;
    const int* dstA = ei + E;

    char* w = (char*)d_ws;
    auto alloc = [&](size_t b) -> void* {
        void* p = (void*)w;
        w += (b + 255) & ~(size_t)255;
        return p;
    };
    unsigned short* xbf  = (unsigned short*)alloc((size_t)N * 512 * 2);
    unsigned short* w1t  = (unsigned short*)alloc((size_t)512 * 512 * 2);
    unsigned short* xw1  = (unsigned short*)alloc((size_t)N * 512 * 2);   // bf16 output of GEMM1
    float* hbuf = (float*)alloc((size_t)N * 512 * 4);
    float* a_s1 = (float*)alloc((size_t)N * 8 * 4);
    float* a_d1 = (float*)alloc((size_t)N * 8 * 4);
    float* m1   = (float*)alloc((size_t)N * 8 * 4);
    float* d1   = (float*)alloc((size_t)N * 8 * 4);
    float* wb1  = (float*)alloc((size_t)Ep * 8 * 4);
    float* hw2  = (float*)alloc((size_t)N * 32 * 4);
    float* a_s2 = (float*)alloc((size_t)N * 4);
    float* a_d2 = (float*)alloc((size_t)N * 4);
    float* m2   = (float*)alloc((size_t)N * 4);
    float* d2   = (float*)alloc((size_t)N * 4);
    float* wb2  = (float*)alloc((size_t)Ep * 4);
    int* deg    = (int*)alloc((size_t)N * 4);
    int* incl   = (int*)alloc((size_t)N * 4);
    int* part   = (int*)alloc(256 * 4);
    int* off    = (int*)alloc((size_t)(N + 1) * 4);
    int* cursor = (int*)alloc((size_t)N * 4);
    int* eid_s  = (int*)alloc((size_t)Ep * 4);
    int* src_s  = (int*)alloc((size_t)Ep * 4);

    int egrid = (Ep + 255) / 256;
    int sgrid = (N + 255) / 256;

    k_init<<<(N * 8 + 255) / 256, 256, 0, stream>>>(m1, d1, m2, d2, deg, N);

    // casts
    k_cast_x<<<((N * 512 / 4) + 255) / 256, 256, 0, stream>>>(x, xbf, N * 512 / 4);
    {
        dim3 gt(16, 16);
        k_cast_w1t<<<gt, 256, 0, stream>>>(W1, w1t);
    }

    // CSR (shared by both layers)
    k_deg<<<egrid, 256, 0, stream>>>(dstA, E, Ep, deg);
    k_scan1<<<sgrid, 256, 0, stream>>>(deg, incl, part, N);
    k_scan2<<<1, 256, 0, stream>>>(part, sgrid);
    k_scan3<<<sgrid, 256, 0, stream>>>(incl, part, deg, off, cursor, N);
    k_scatter<<<egrid, 256, 0, stream>>>(srcA, dstA, E, Ep, cursor, eid_s, src_s);

    // layer 1
    {
        dim3 g1((N + 127) / 128, 512 / 128);
        k_gemm1_mfma<<<g1, 256, 0, stream>>>(xbf, w1t, xw1, N);
    }
    k_attn1<<<(N * 8 + 3) / 4, 256, 0, stream>>>(xw1, as1, ad1, a_s1, a_d1, N);
    k_edge_max<8><<<egrid, 256, 0, stream>>>(srcA, dstA, E, Ep, a_s1, a_d1, m1);
    k_edge_expsum<8><<<egrid, 256, 0, stream>>>(srcA, dstA, E, Ep, a_s1, a_d1, m1, wb1, d1);
    k_agg1<<<N, 256, 0, stream>>>(xw1, wb1, d1, off, eid_s, src_s, b1, hbuf, N);

    // layer 2
    k_gemm2<<<(N + 7) / 8, 256, 0, stream>>>(hbuf, W2, hw2, N);
    k_attn2<<<(N * 32 + 255) / 256, 256, 0, stream>>>(hw2, as2, ad2, a_s2, a_d2, N);
    k_edge_max<1><<<egrid, 256, 0, stream>>>(srcA, dstA, E, Ep, a_s2, a_d2, m2);
    k_edge_expsum<1><<<egrid, 256, 0, stream>>>(srcA, dstA, E, Ep, a_s2, a_d2, m2, wb2, d2);
    k_agg2<<<(N + 7) / 8, 256, 0, stream>>>(hw2, wb2, d2, off, eid_s, src_s, b2, out, N);
}

// Round 3
// 381.532 us; speedup vs baseline: 2.0880x; 1.7280x over previous
//
#include <hip/hip_runtime.h>
#include <math.h>

#define NEG_SLOPE 0.2f
#define SM_EPS 1e-16f

typedef short short8 __attribute__((ext_vector_type(8)));
typedef float floatx4 __attribute__((ext_vector_type(4)));

// ---------------- helpers ----------------

__device__ inline unsigned short f2bf(float x) {
    unsigned int u = __float_as_uint(x);
    unsigned int r = (u + 0x7FFFu + ((u >> 16) & 1u)) >> 16;
    return (unsigned short)r;
}

__device__ inline float bf2f(unsigned short h) {
    return __uint_as_float(((unsigned int)h) << 16);
}

__device__ inline void get_edge(const int* __restrict__ srcA, const int* __restrict__ dstA,
                                int e, int E, int& s, int& d) {
    if (e < E) { s = srcA[e]; d = dstA[e]; }
    else { s = e - E; d = e - E; }   // self-loops appended after real edges
}

// ---------------- init ----------------

__global__ __launch_bounds__(256) void k_init(int* deg, int N) {
    int i = blockIdx.x * 256 + threadIdx.x;
    if (i < N) deg[i] = 0;
}

// ---------------- casts ----------------

__global__ __launch_bounds__(256) void k_cast_x(const float* __restrict__ x,
                                                unsigned short* __restrict__ xb, int total4) {
    int i = (blockIdx.x * 256 + threadIdx.x) * 4;
    if (i >= total4 * 4) return;
    float4 v = *(const float4*)(x + i);
    ushort4 o;
    o.x = f2bf(v.x); o.y = f2bf(v.y); o.z = f2bf(v.z); o.w = f2bf(v.w);
    *(ushort4*)(xb + i) = o;
}

// W1 is [K=512][N=512]; produce W1t bf16 [n][k]
__global__ __launch_bounds__(256) void k_cast_w1t(const float* __restrict__ W,
                                                  unsigned short* __restrict__ Wt) {
    __shared__ float tile[32][33];
    int bx = blockIdx.x * 32;   // k base
    int by = blockIdx.y * 32;   // n base
    int tx = threadIdx.x & 31, ty = threadIdx.x >> 5;  // 32x8
    #pragma unroll
    for (int i = 0; i < 32; i += 8)
        tile[ty + i][tx] = W[(size_t)(bx + ty + i) * 512 + by + tx];
    __syncthreads();
    #pragma unroll
    for (int i = 0; i < 32; i += 8)
        Wt[(size_t)(by + ty + i) * 512 + bx + tx] = f2bf(tile[tx][ty + i]);
}

// ---------------- CSR build ----------------

__global__ __launch_bounds__(256) void k_deg(const int* __restrict__ dstA, int E, int Ep,
                                             int* __restrict__ deg) {
    int e = blockIdx.x * 256 + threadIdx.x;
    if (e >= Ep) return;
    int d = (e < E) ? dstA[e] : (e - E);
    atomicAdd(&deg[d], 1);
}

__global__ __launch_bounds__(256) void k_scan1(const int* __restrict__ deg, int* __restrict__ incl,
                                               int* __restrict__ part, int N) {
    __shared__ int sm[256];
    int t = threadIdx.x;
    int i = blockIdx.x * 256 + t;
    int v = (i < N) ? deg[i] : 0;
    sm[t] = v; __syncthreads();
    for (int o = 1; o < 256; o <<= 1) {
        int x = (t >= o) ? sm[t - o] : 0;
        __syncthreads();
        sm[t] += x;
        __syncthreads();
    }
    if (i < N) incl[i] = sm[t];
    if (t == 255) part[blockIdx.x] = sm[255];
}

__global__ __launch_bounds__(256) void k_scan2(int* __restrict__ part, int nb) {
    __shared__ int sm[256];
    int t = threadIdx.x;
    int v = (t < nb) ? part[t] : 0;
    sm[t] = v; __syncthreads();
    for (int o = 1; o < 256; o <<= 1) {
        int x = (t >= o) ? sm[t - o] : 0;
        __syncthreads();
        sm[t] += x;
        __syncthreads();
    }
    if (t < nb) part[t] = sm[t] - v;   // exclusive
}

__global__ __launch_bounds__(256) void k_scan3(const int* __restrict__ incl, const int* __restrict__ part,
                                               const int* __restrict__ deg, int* __restrict__ off,
                                               int* __restrict__ cursor, int N) {
    int i = blockIdx.x * 256 + threadIdx.x;
    if (i >= N) return;
    int v = incl[i] + part[blockIdx.x];   // inclusive scan value
    off[i + 1] = v;
    cursor[i] = v - deg[i];
    if (i == 0) off[0] = 0;
}

__global__ __launch_bounds__(256) void k_scatter(const int* __restrict__ srcA, const int* __restrict__ dstA,
                                                 int E, int Ep, int* __restrict__ cursor,
                                                 int* __restrict__ src_s) {
    int e = blockIdx.x * 256 + threadIdx.x;
    if (e >= Ep) return;
    int s, d; get_edge(srcA, dstA, e, E, s, d);
    int p = atomicAdd(&cursor[d], 1);
    src_s[p] = s;
}

// ---------------- GEMM1 (bf16 MFMA): xw1 = x @ W1, output bf16 ----------------

__global__ __launch_bounds__(256) void k_gemm1_mfma(const unsigned short* __restrict__ A,
                                                    const unsigned short* __restrict__ Bt,
                                                    unsigned short* __restrict__ C, int M) {
    const int K = 512;
    __shared__ unsigned short As[128 * 40];
    __shared__ unsigned short Bs[128 * 40];
    int t = threadIdx.x;
    int lane = t & 63;
    int w = t >> 6;
    int row0 = blockIdx.x * 128;
    int col0 = blockIdx.y * 128;
    int wm = (w >> 1) * 64, wn = (w & 1) * 64;
    int l15 = lane & 15, q = lane >> 4;

    floatx4 acc[4][4] = {};

    for (int k0 = 0; k0 < K; k0 += 32) {
        #pragma unroll
        for (int r = 0; r < 2; ++r) {
            int flat = r * 2048 + t * 8;
            int m = flat >> 5, kk = flat & 31;
            uint4 va = make_uint4(0u, 0u, 0u, 0u);
            int gr = row0 + m;
            if (gr < M) va = *(const uint4*)(A + (size_t)gr * K + k0 + kk);
            *(uint4*)(&As[m * 40 + kk]) = va;
            uint4 vb = *(const uint4*)(Bt + (size_t)(col0 + m) * K + k0 + kk);
            *(uint4*)(&Bs[m * 40 + kk]) = vb;
        }
        __syncthreads();
        short8 af[4], bfr[4];
        #pragma unroll
        for (int i = 0; i < 4; ++i)
            af[i] = *(const short8*)(&As[(wm + i * 16 + l15) * 40 + q * 8]);
        #pragma unroll
        for (int j = 0; j < 4; ++j)
            bfr[j] = *(const short8*)(&Bs[(wn + j * 16 + l15) * 40 + q * 8]);
        #pragma unroll
        for (int i = 0; i < 4; ++i)
            #pragma unroll
            for (int j = 0; j < 4; ++j)
                acc[i][j] = __builtin_amdgcn_mfma_f32_16x16x32_bf16(af[i], bfr[j], acc[i][j], 0, 0, 0);
        __syncthreads();
    }
    #pragma unroll
    for (int i = 0; i < 4; ++i) {
        #pragma unroll
        for (int p = 0; p < 4; ++p) {
            int r = row0 + wm + i * 16 + q * 4 + p;
            if (r < M) {
                #pragma unroll
                for (int j = 0; j < 4; ++j) {
                    int c = col0 + wn + j * 16 + l15;
                    C[(size_t)r * 512 + c] = f2bf(acc[i][j][p]);
                }
            }
        }
    }
}

// ---------------- attention dots ----------------

__global__ __launch_bounds__(256) void k_attn1(const unsigned short* __restrict__ xw,
                                               const float* __restrict__ att_s,
                                               const float* __restrict__ att_d, float* __restrict__ a_s,
                                               float* __restrict__ a_d, int N) {
    int wid = (blockIdx.x * 256 + threadIdx.x) >> 6;
    int lane = threadIdx.x & 63;
    int n = wid >> 3, h = wid & 7;
    if (n >= N) return;
    float v = bf2f(xw[(size_t)n * 512 + h * 64 + lane]);
    float ps = v * att_s[h * 64 + lane];
    float pd = v * att_d[h * 64 + lane];
    #pragma unroll
    for (int m = 32; m >= 1; m >>= 1) {
        ps += __shfl_xor(ps, m);
        pd += __shfl_xor(pd, m);
    }
    if (lane == 0) { a_s[n * 8 + h] = ps; a_d[n * 8 + h] = pd; }
}

__global__ __launch_bounds__(256) void k_attn2(const float* __restrict__ hw2, const float* __restrict__ att_s,
                                               const float* __restrict__ att_d, float* __restrict__ a_s,
                                               float* __restrict__ a_d, int N) {
    int idx = blockIdx.x * 256 + threadIdx.x;
    int n = idx >> 5, lane = idx & 31;
    if (n >= N) return;
    float v = hw2[(size_t)n * 32 + lane];
    float ps = v * att_s[lane];
    float pd = v * att_d[lane];
    #pragma unroll
    for (int m = 16; m >= 1; m >>= 1) {
        ps += __shfl_xor(ps, m, 32);
        pd += __shfl_xor(pd, m, 32);
    }
    if (lane == 0) { a_s[n] = ps; a_d[n] = pd; }
}

// ---------------- per-node CSR softmax (no atomics) ----------------

// H=8: one wave per node. lane = (slot i = l>>3, head h = l&7).
// Pass 1: e -> wbuf[p*8+h] (raw), online (m,s). Reduce over slots. Pass 2: normalize.
__global__ __launch_bounds__(256) void k_soft1(const float* __restrict__ a_s,
                                               const float* __restrict__ a_d,
                                               const int* __restrict__ off,
                                               const int* __restrict__ src_s,
                                               float* __restrict__ wbuf, int N) {
    int w = threadIdx.x >> 6;
    int lane = threadIdx.x & 63;
    int n = blockIdx.x * 4 + w;
    if (n >= N) return;
    int i = lane >> 3, h = lane & 7;
    int p0 = off[n], p1 = off[n + 1];
    float adv = a_d[n * 8 + h];
    float m = -INFINITY, s = 0.f;
    for (int p = p0 + i; p < p1; p += 8) {
        int sc = src_s[p];
        float e = a_s[sc * 8 + h] + adv;
        e = e > 0.f ? e : NEG_SLOPE * e;
        wbuf[(size_t)p * 8 + h] = e;
        float M = fmaxf(m, e);
        s = s * expf(m - M) + expf(e - M);
        m = M;
    }
    #pragma unroll
    for (int mask = 8; mask <= 32; mask <<= 1) {
        float om = __shfl_xor(m, mask);
        float os = __shfl_xor(s, mask);
        float M = fmaxf(m, om);
        s = (M == -INFINITY) ? 0.f : s * expf(m - M) + os * expf(om - M);
        m = M;
    }
    float inv = 1.f / (s + SM_EPS);
    for (int p = p0 + i; p < p1; p += 8) {
        float e = wbuf[(size_t)p * 8 + h];
        wbuf[(size_t)p * 8 + h] = expf(e - m) * inv;
    }
}

// H=1: one wave per node, lanes stride 64 over edges.
__global__ __launch_bounds__(256) void k_soft2(const float* __restrict__ a_s,
                                               const float* __restrict__ a_d,
                                               const int* __restrict__ off,
                                               const int* __restrict__ src_s,
                                               float* __restrict__ wbuf, int N) {
    int w = threadIdx.x >> 6;
    int lane = threadIdx.x & 63;
    int n = blockIdx.x * 4 + w;
    if (n >= N) return;
    int p0 = off[n], p1 = off[n + 1];
    float adv = a_d[n];
    float m = -INFINITY, s = 0.f;
    for (int p = p0 + lane; p < p1; p += 64) {
        int sc = src_s[p];
        float e = a_s[sc] + adv;
        e = e > 0.f ? e : NEG_SLOPE * e;
        wbuf[p] = e;
        float M = fmaxf(m, e);
        s = s * expf(m - M) + expf(e - M);
        m = M;
    }
    #pragma unroll
    for (int mask = 1; mask <= 32; mask <<= 1) {
        float om = __shfl_xor(m, mask);
        float os = __shfl_xor(s, mask);
        float M = fmaxf(m, om);
        s = (M == -INFINITY) ? 0.f : s * expf(m - M) + os * expf(om - M);
        m = M;
    }
    float inv = 1.f / (s + SM_EPS);
    for (int p = p0 + lane; p < p1; p += 64) {
        float e = wbuf[p];
        wbuf[p] = expf(e - m) * inv;
    }
}

// ---------------- aggregation ----------------

// layer 1: block per node; thread t -> channels (2t, 2t+1), head = t>>5.
__global__ __launch_bounds__(256) void k_agg1(const unsigned short* __restrict__ xw,
                                              const float* __restrict__ wbuf,
                                              const int* __restrict__ off,
                                              const int* __restrict__ src_s,
                                              const float* __restrict__ bias, float* __restrict__ hout, int N) {
    int n = blockIdx.x;
    int t = threadIdx.x;
    int h = t >> 5;
    float acc0 = 0.f, acc1 = 0.f;
    int p0 = off[n], p1 = off[n + 1];
    for (int p = p0; p < p1; ++p) {
        int s = src_s[p];
        float wv = wbuf[(size_t)p * 8 + h];
        unsigned int u = *(const unsigned int*)(xw + (size_t)s * 512 + 2 * t);
        acc0 = fmaf(wv, bf2f((unsigned short)(u & 0xFFFFu)), acc0);
        acc1 = fmaf(wv, bf2f((unsigned short)(u >> 16)), acc1);
    }
    acc0 += bias[2 * t];
    acc1 += bias[2 * t + 1];
    float2 o;
    o.x = acc0 > 0.f ? acc0 : expm1f(acc0);
    o.y = acc1 > 0.f ? acc1 : expm1f(acc1);
    *(float2*)(hout + (size_t)n * 512 + 2 * t) = o;
}

// ---------------- GEMM2: hw2 = h @ W2  (Mx512 @ 512x32) ----------------

__global__ __launch_bounds__(256) void k_gemm2(const float* __restrict__ Hm, const float* __restrict__ W2,
                                               float* __restrict__ O, int M) {
    __shared__ float hs[8][512];
    int tid = threadIdx.x;
    int n0 = blockIdx.x * 8;
    for (int i = tid; i < 8 * 512; i += 256) {
        int r = i >> 9, c = i & 511;
        int gr = n0 + r;
        hs[r][c] = (gr < M) ? Hm[(size_t)gr * 512 + c] : 0.f;
    }
    __syncthreads();
    int r = tid >> 5, c = tid & 31;
    float acc = 0.f;
    #pragma unroll 8
    for (int k = 0; k < 512; ++k)
        acc = fmaf(hs[r][k], W2[k * 32 + c], acc);
    int gr = n0 + r;
    if (gr < M) O[(size_t)gr * 32 + c] = acc;
}

// layer 2 aggregation + bias + log_softmax -> d_out. 32 lanes per node, 8 nodes/block.
__global__ __launch_bounds__(256) void k_agg2(const float* __restrict__ hw2, const float* __restrict__ wbuf,
                                              const int* __restrict__ off,
                                              const int* __restrict__ src_s,
                                              const float* __restrict__ bias, float* __restrict__ outp, int N) {
    int sub = threadIdx.x >> 5;
    int lane = threadIdx.x & 31;
    int n = blockIdx.x * 8 + sub;
    if (n >= N) return;
    float acc = 0.f;
    int p0 = off[n], p1 = off[n + 1];
    for (int p = p0; p < p1; ++p) {
        int s = src_s[p];
        acc = fmaf(wbuf[p], hw2[(size_t)s * 32 + lane], acc);
    }
    acc += bias[lane];
    float mx = acc;
    #pragma unroll
    for (int m = 16; m >= 1; m >>= 1) mx = fmaxf(mx, __shfl_xor(mx, m, 32));
    float ex = expf(acc - mx);
    float sum = ex;
    #pragma unroll
    for (int m = 16; m >= 1; m >>= 1) sum += __shfl_xor(sum, m, 32);
    outp[(size_t)n * 32 + lane] = (acc - mx) - logf(sum);
}

// ---------------- launch ----------------

extern "C" void kernel_launch(void* const* d_in, const int* in_sizes, int n_in,
                              void* d_out, int out_size, void* d_ws, size_t ws_size,
                              hipStream_t stream) {
    const float* x   = (const float*)d_in[0];
    const int*   ei  = (const int*)d_in[1];
    const float* W1  = (const float*)d_in[2];
    const float* as1 = (const float*)d_in[3];
    const float* ad1 = (const float*)d_in[4];
    const float* b1  = (const float*)d_in[5];
    const float* W2  = (const float*)d_in[6];
    const float* as2 = (const float*)d_in[7];
    const float* ad2 = (const float*)d_in[8];
    const float* b2  = (const float*)d_in[9];
    float* out = (float*)d_out;

    const int F = 512;
    const int N = in_sizes[0] / F;     // 20000
    const int E = in_sizes[1] / 2;     // 320000
    const int Ep = E + N;              // with self-loops
    const int* srcA = ei;
    const int* dstA = ei + E;

    char* w = (char*)d_ws;
    auto alloc = [&](size_t b) -> void* {
        void* p = (void*)w;
        w += (b + 255) & ~(size_t)255;
        return p;
    };
    unsigned short* xbf  = (unsigned short*)alloc((size_t)N * 512 * 2);
    unsigned short* w1t  = (unsigned short*)alloc((size_t)512 * 512 * 2);
    unsigned short* xw1  = (unsigned short*)alloc((size_t)N * 512 * 2);
    float* hbuf = (float*)alloc((size_t)N * 512 * 4);
    float* a_s1 = (float*)alloc((size_t)N * 8 * 4);
    float* a_d1 = (float*)alloc((size_t)N * 8 * 4);
    float* wb1  = (float*)alloc((size_t)Ep * 8 * 4);   // CSR-ordered alpha (layer 1)
    float* hw2  = (float*)alloc((size_t)N * 32 * 4);
    float* a_s2 = (float*)alloc((size_t)N * 4);
    float* a_d2 = (float*)alloc((size_t)N * 4);
    float* wb2  = (float*)alloc((size_t)Ep * 4);       // CSR-ordered alpha (layer 2)
    int* deg    = (int*)alloc((size_t)N * 4);
    int* incl   = (int*)alloc((size_t)N * 4);
    int* part   = (int*)alloc(256 * 4);
    int* off    = (int*)alloc((size_t)(N + 1) * 4);
    int* cursor = (int*)alloc((size_t)N * 4);
    int* src_s  = (int*)alloc((size_t)Ep * 4);

    int egrid = (Ep + 255) / 256;
    int sgrid = (N + 255) / 256;
    int ngrid4 = (N + 3) / 4;

    k_init<<<sgrid, 256, 0, stream>>>(deg, N);

    // casts
    k_cast_x<<<((N * 512 / 4) + 255) / 256, 256, 0, stream>>>(x, xbf, N * 512 / 4);
    {
        dim3 gt(16, 16);
        k_cast_w1t<<<gt, 256, 0, stream>>>(W1, w1t);
    }

    // CSR (shared by both layers)
    k_deg<<<egrid, 256, 0, stream>>>(dstA, E, Ep, deg);
    k_scan1<<<sgrid, 256, 0, stream>>>(deg, incl, part, N);
    k_scan2<<<1, 256, 0, stream>>>(part, sgrid);
    k_scan3<<<sgrid, 256, 0, stream>>>(incl, part, deg, off, cursor, N);
    k_scatter<<<egrid, 256, 0, stream>>>(srcA, dstA, E, Ep, cursor, src_s);

    // layer 1
    {
        dim3 g1((N + 127) / 128, 512 / 128);
        k_gemm1_mfma<<<g1, 256, 0, stream>>>(xbf, w1t, xw1, N);
    }
    k_attn1<<<(N * 8 + 3) / 4, 256, 0, stream>>>(xw1, as1, ad1, a_s1, a_d1, N);
    k_soft1<<<ngrid4, 256, 0, stream>>>(a_s1, a_d1, off, src_s, wb1, N);
    k_agg1<<<N, 256, 0, stream>>>(xw1, wb1, off, src_s, b1, hbuf, N);

    // layer 2
    k_gemm2<<<(N + 7) / 8, 256, 0, stream>>>(hbuf, W2, hw2, N);
    k_attn2<<<(N * 32 + 255) / 256, 256, 0, stream>>>(hw2, as2, ad2, a_s2, a_d2, N);
    k_soft2<<<ngrid4, 256, 0, stream>>>(a_s2, a_d2, off, src_s, wb2, N);
    k_agg2<<<(N + 7) / 8, 256, 0, stream>>>(hw2, wb2, off, src_s, b2, out, N);
}